// Round 7
// baseline (2105.103 us; speedup 1.0000x reference)
//
#include <hip/hip_runtime.h>
#include <hip/hip_bf16.h>

// 4 stacked LSTM layers (512->64, 64->64, 64->6, 6->6) + FC(6->6).
// B=64, T=1024, M = B*T = 65536.
//
// R6: scan64_dot — inner product emitted as inline-asm v_dot2_f32_f16 with
//     "v"-constrained weights (forces arch-VGPR residency; R4/R5 showed
//     VGPR_Count 88/84 < the 128 weight regs -> AGPR/expansion tax,
//     ~560 VALU insts/step vs ~195 floor) and "s"-constrained h broadcast
//     (v_readlane -> SGPR, VOP3P may read one SGPR). waves_per_eu(1,1) for
//     the full register budget. v_rcp-based activations (no f32 div chain).

#define B_SZ 64
#define T_SZ 1024
#define M_SZ (B_SZ * T_SZ)

typedef _Float16 h2   __attribute__((ext_vector_type(2)));
typedef _Float16 h8   __attribute__((ext_vector_type(8)));
typedef float    f32x4 __attribute__((ext_vector_type(4)));

__device__ __forceinline__ float sigm_f(float x) {
    // 1/(1+e^-x) with v_rcp (avoids fp32 div expansion); ~1e-6 rel err
    return __builtin_amdgcn_rcpf(1.0f + __expf(-x));
}
__device__ __forceinline__ float tanh_f(float x) {
    return 2.0f * __builtin_amdgcn_rcpf(1.0f + __expf(-2.0f * x)) - 1.0f;
}

// ---------------- fp32 -> f16 converter (for W_ih weights) ------------------
__global__ __launch_bounds__(256) void f32_to_f16(const float* __restrict__ src,
                                                  _Float16* __restrict__ dst, int n) {
    const int i = blockIdx.x * 256 + threadIdx.x;
    if (i < n) dst[i] = (_Float16)src[i];
}

// ---------------- MFMA input-projection GEMM --------------------------------
// out[m, g] = bias[g] + sum_k X[m,k] * W[g,k], G = 256 gates, K in {512, 64}.
template <int K>
__global__ __launch_bounds__(256) void gemm_mfma(const float* __restrict__ X,
                                                 const _Float16* __restrict__ W16,
                                                 const float* __restrict__ bias,
                                                 float* __restrict__ out) {
    const int m0   = blockIdx.x * 64;
    const int tid  = threadIdx.x;
    const int wv   = tid >> 6;
    const int lane = tid & 63;
    const int lh   = lane & 15;
    const int quad = lane >> 4;
    const int n0   = wv * 64;

    __shared__ __align__(16) _Float16 Als[64 * 32];   // 64 rows x 32 k (f16)

    f32x4 acc[4][4];
#pragma unroll
    for (int nt = 0; nt < 4; ++nt) {
        const float bg = bias[n0 + nt * 16 + lh];
#pragma unroll
        for (int mt = 0; mt < 4; ++mt) {
            acc[mt][nt].x = bg; acc[mt][nt].y = bg;
            acc[mt][nt].z = bg; acc[mt][nt].w = bg;
        }
    }

    const int srow = tid >> 2;
    const int sk8  = tid & 3;
    const int sdst = srow * 32 + ((sk8 ^ (srow & 3)) * 8);

    for (int k0 = 0; k0 < K; k0 += 32) {
        const float* xr = X + (size_t)(m0 + srow) * K + k0 + sk8 * 8;
        const float4 a4 = ((const float4*)xr)[0];
        const float4 b4 = ((const float4*)xr)[1];
        h8 bfrag[4];
#pragma unroll
        for (int nt = 0; nt < 4; ++nt) {
            bfrag[nt] = *(const h8*)&W16[(size_t)(n0 + nt * 16 + lh) * K + k0 + quad * 8];
        }
        h8 hv;
        hv[0] = (_Float16)a4.x; hv[1] = (_Float16)a4.y;
        hv[2] = (_Float16)a4.z; hv[3] = (_Float16)a4.w;
        hv[4] = (_Float16)b4.x; hv[5] = (_Float16)b4.y;
        hv[6] = (_Float16)b4.z; hv[7] = (_Float16)b4.w;

        __syncthreads();
        *(h8*)&Als[sdst] = hv;
        __syncthreads();

        h8 afrag[4];
#pragma unroll
        for (int mt = 0; mt < 4; ++mt) {
            const int row = mt * 16 + lh;
            afrag[mt] = *(const h8*)&Als[row * 32 + ((quad ^ (row & 3)) * 8)];
        }
#pragma unroll
        for (int mt = 0; mt < 4; ++mt)
#pragma unroll
            for (int nt = 0; nt < 4; ++nt)
                acc[mt][nt] = __builtin_amdgcn_mfma_f32_16x16x32_f16(
                    afrag[mt], bfrag[nt], acc[mt][nt], 0, 0, 0);
    }

#pragma unroll
    for (int mt = 0; mt < 4; ++mt)
#pragma unroll
        for (int nt = 0; nt < 4; ++nt)
#pragma unroll
            for (int r = 0; r < 4; ++r)
                out[(size_t)(m0 + mt * 16 + quad * 4 + r) * 256 + n0 + nt * 16 + lh] =
                    acc[mt][nt][r];
}

// ---------------- generic small GEMM (thread per output element) -----------
__global__ void gemm_naive(const float* __restrict__ X, const float* __restrict__ W,
                           const float* __restrict__ bias, float* __restrict__ out,
                           int M, int D, int G) {
    const int idx = blockIdx.x * 256 + threadIdx.x;
    if (idx >= M * G) return;
    const int m = idx / G, g = idx % G;
    float acc = bias[g];
    const float* xr = X + (size_t)m * D;
    const float* wr = W + (size_t)g * D;
    for (int k = 0; k < D; ++k) acc += xr[k] * wr[k];
    out[idx] = acc;
}

// ---------------- LSTM scan H=64: single wave, asm dot2 ---------------------
// Lane u owns unit u: 4 W_hh rows as 128 packed-f16 dwords ("v"-pinned by
// asm constraints), h[u], c[u]. Per step: h -> f16, DPP-pair, 32 readlane
// SGPR broadcasts; 128 v_dot2_f32_f16 (VGPR weight x SGPR h-pair).
__global__ __launch_bounds__(64)
__attribute__((amdgpu_waves_per_eu(1, 1)))
void scan64_dot(const float* __restrict__ xg,
                const float* __restrict__ whh,
                float* __restrict__ hout) {
    const int b = blockIdx.x;
    const int u = threadIdx.x;

    // w[g][k2] = bit-packed {f16(whh[(g*64+u)*64+2k2]), f16(...+2k2+1)}
    int w[4][32];
#pragma unroll
    for (int g = 0; g < 4; ++g) {
        const float* wr = whh + (size_t)(g * 64 + u) * 64;
#pragma unroll
        for (int k2 = 0; k2 < 32; ++k2) {
            const _Float16 lo = (_Float16)wr[2 * k2];
            const _Float16 hi = (_Float16)wr[2 * k2 + 1];
            w[g][k2] = (int)__builtin_bit_cast(unsigned short, lo) |
                       ((int)__builtin_bit_cast(unsigned short, hi) << 16);
        }
    }

    const float* xgb = xg + (size_t)b * T_SZ * 256;
    float xp[4][4];
#pragma unroll
    for (int s = 0; s < 4; ++s)
#pragma unroll
        for (int g = 0; g < 4; ++g) xp[s][g] = xgb[s * 256 + g * 64 + u];

    float c = 0.0f, h_own = 0.0f;
    float* hrow = hout + (size_t)b * T_SZ * 64;

    for (int t = 0; t < T_SZ; ++t) {
        const int s = t & 3;

        // pack {h[2i], h[2i+1]} into even lanes
        const _Float16 hf = (_Float16)h_own;
        const int hb = (int)__builtin_bit_cast(unsigned short, hf);
        const int nb = __builtin_amdgcn_update_dpp(0, hb, 0xB1, 0xF, 0xF, true);
        const int pk = hb | (nb << 16);

        float a0 = xp[s][0];
        float a1 = xp[s][1];
        float a2 = xp[s][2];
        float a3 = xp[s][3];
#pragma unroll
        for (int k2 = 0; k2 < 32; ++k2) {
            const int hs = __builtin_amdgcn_readlane(pk, 2 * k2);
            asm("v_dot2_f32_f16 %0, %4, %8, %0\n\t"
                "v_dot2_f32_f16 %1, %5, %8, %1\n\t"
                "v_dot2_f32_f16 %2, %6, %8, %2\n\t"
                "v_dot2_f32_f16 %3, %7, %8, %3"
                : "+v"(a0), "+v"(a1), "+v"(a2), "+v"(a3)
                : "v"(w[0][k2]), "v"(w[1][k2]), "v"(w[2][k2]), "v"(w[3][k2]),
                  "s"(hs));
        }

        // prefetch xg for t+4 — unclamped (reads past-end land in the
        // adjacent ws region, mapped; values never consumed for t+4 >= T)
#pragma unroll
        for (int g = 0; g < 4; ++g)
            xp[s][g] = xgb[(size_t)(t + 4) * 256 + g * 64 + u];

        const float iv = sigm_f(a0);
        const float fv = sigm_f(a1);
        const float gv = tanh_f(a2);
        const float ov = sigm_f(a3);
        c = fv * c + iv * gv;
        h_own = ov * tanh_f(c);

        hrow[t * 64 + u] = h_own;
    }
}

// ---------------- fused L3 + L4 + FC, one wave per batch --------------------
// lanes 0..5: layer-3 unit u; lanes 6..11: layer-4 unit u one step behind;
// FC folded into the h4 broadcast. readlane broadcast, no LDS, no barriers.
__global__ __launch_bounds__(64)
__attribute__((amdgpu_waves_per_eu(1, 1)))
void scan66(const float* __restrict__ xg3,
            const float* __restrict__ whh3,
            const float* __restrict__ wih4,
            const float* __restrict__ whh4,
            const float* __restrict__ b4,
            const float* __restrict__ fcw,
            const float* __restrict__ fcb,
            float* __restrict__ out) {
    const int b    = blockIdx.x;
    const int lane = threadIdx.x & 63;
    const bool is_l4 = (lane >= 6 && lane < 12);
    const int u = is_l4 ? (lane - 6) : (lane < 6 ? lane : 0);

    float w[4][12];
#pragma unroll
    for (int g = 0; g < 4; ++g) {
#pragma unroll
        for (int k = 0; k < 6; ++k) {
            const float wl3  = whh3[(g * 6 + u) * 6 + k];
            const float wl4i = wih4[(g * 6 + u) * 6 + k];
            const float wl4h = whh4[(g * 6 + u) * 6 + k];
            w[g][k]     = is_l4 ? wl4i : wl3;
            w[g][6 + k] = is_l4 ? wl4h : 0.0f;
        }
    }
    float bias[4], fw[6];
#pragma unroll
    for (int g = 0; g < 4; ++g) bias[g] = is_l4 ? b4[g * 6 + u] : 0.0f;
#pragma unroll
    for (int k = 0; k < 6; ++k) fw[k] = fcw[u * 6 + k];
    const float fb = fcb[u];

    const float* xgb = xg3 + (size_t)b * T_SZ * 24;
    float xv[4][4];
#pragma unroll
    for (int s = 0; s < 4; ++s)
#pragma unroll
        for (int g = 0; g < 4; ++g) xv[s][g] = xgb[s * 24 + g * 6 + u];

    float* outb = out + (size_t)b * T_SZ * 6;
    float h_own = 0.0f, c = 0.0f;

    for (int t4 = 0; t4 < T_SZ + 4; t4 += 4) {
#pragma unroll
        for (int s = 0; s < 4; ++s) {
            const int t = t4 + s;
            const int hbits = __builtin_bit_cast(int, h_own);
            float v[12];
#pragma unroll
            for (int i = 0; i < 12; ++i)
                v[i] = __builtin_bit_cast(float, __builtin_amdgcn_readlane(hbits, i));

            if (is_l4 && t >= 2 && t < T_SZ + 2) {
                outb[(size_t)(t - 2) * 6 + u] =
                    fb + fw[0]*v[6] + fw[1]*v[7] + fw[2]*v[8] +
                         fw[3]*v[9] + fw[4]*v[10] + fw[5]*v[11];
            }

            float p[4];
#pragma unroll
            for (int g = 0; g < 4; ++g) {
                float a = is_l4 ? bias[g] : xv[s][g];
#pragma unroll
                for (int k = 0; k < 12; ++k) a += w[g][k] * v[k];
                p[g] = a;
            }
            {
                const int tp = (t + 4 < T_SZ) ? (t + 4) : (T_SZ - 1);
#pragma unroll
                for (int g = 0; g < 4; ++g)
                    xv[s][g] = xgb[(size_t)tp * 24 + g * 6 + u];
            }
            const float iv = sigm_f(p[0]);
            const float fv = sigm_f(p[1]);
            const float gv = tanh_f(p[2]);
            const float ov = sigm_f(p[3]);
            const float en = (is_l4 && t == 0) ? 0.0f : 1.0f;
            c = en * (fv * c + iv * gv);
            h_own = en * (ov * tanh_f(c));
        }
    }
}

extern "C" void kernel_launch(void* const* d_in, const int* in_sizes, int n_in,
                              void* d_out, int out_size, void* d_ws, size_t ws_size,
                              hipStream_t stream) {
    const float* x      = (const float*)d_in[0];
    const float* w1_ih0 = (const float*)d_in[1];
    const float* w1_hh0 = (const float*)d_in[2];
    const float* b1_0   = (const float*)d_in[3];
    const float* w1_ih1 = (const float*)d_in[4];
    const float* w1_hh1 = (const float*)d_in[5];
    const float* b1_1   = (const float*)d_in[6];
    const float* w2_ih0 = (const float*)d_in[7];
    const float* w2_hh0 = (const float*)d_in[8];
    const float* b2_0   = (const float*)d_in[9];
    const float* w2_ih1 = (const float*)d_in[10];
    const float* w2_hh1 = (const float*)d_in[11];
    const float* b2_1   = (const float*)d_in[12];
    const float* fc_w   = (const float*)d_in[13];
    const float* fc_b   = (const float*)d_in[14];
    float* out = (float*)d_out;

    const int M = M_SZ;
    float* xg = (float*)d_ws;                  // M*256 f32 (reused as xg3)
    float* hA = xg + (size_t)M * 256;          // M*64 f32
    float* hB = hA + (size_t)M * 64;           // M*64 f32
    _Float16* w16a = (_Float16*)(hB + (size_t)M * 64);  // 256*512 f16
    _Float16* w16b = w16a + 256 * 512;                  // 256*64  f16

    f32_to_f16<<<(256 * 512 + 255) / 256, 256, 0, stream>>>(w1_ih0, w16a, 256 * 512);
    f32_to_f16<<<(256 * 64 + 255) / 256, 256, 0, stream>>>(w1_ih1, w16b, 256 * 64);

    // L1: 512 -> 64
    gemm_mfma<512><<<M / 64, 256, 0, stream>>>(x, w16a, b1_0, xg);
    scan64_dot<<<B_SZ, 64, 0, stream>>>(xg, w1_hh0, hA);
    // L2: 64 -> 64
    gemm_mfma<64><<<M / 64, 256, 0, stream>>>(hA, w16b, b1_1, xg);
    scan64_dot<<<B_SZ, 64, 0, stream>>>(xg, w1_hh1, hB);
    // L3 input projection: 64 -> 24 gates
    gemm_naive<<<(M * 24 + 255) / 256, 256, 0, stream>>>(hB, w2_ih0, b2_0, xg, M, 64, 24);
    // L3 + L4 + FC fused
    scan66<<<B_SZ, 64, 0, stream>>>(xg, w2_hh0, w2_ih1, w2_hh1, b2_1, fc_w, fc_b, out);
}